// Round 12
// baseline (228.981 us; speedup 1.0000x reference)
//
#include <hip/hip_runtime.h>
#include <hip/hip_bf16.h>

#define DIMK 3
#define NPTS 30
#define KK   181
#define PP   24360
#define DEMB 190
#define VLD  192   // padded vec row stride (bf16 elements)
#define SNP  24576 // logical sort-row length (16*1536)
#define SNPS 24608 // padded sm2TP row stride (+64B, breaks pow2 aliasing)

typedef __attribute__((ext_vector_type(8))) short bf16x8;
typedef __attribute__((ext_vector_type(4))) float f32x4;
typedef __attribute__((ext_vector_type(2))) __fp16 h2;
typedef __attribute__((ext_vector_type(4))) ushort u16x4;
typedef __attribute__((ext_vector_type(4))) unsigned u32x4;

__device__ __forceinline__ ushort f2bf(float f) {
    unsigned u = __float_as_uint(f);
    u += 0x7FFFu + ((u >> 16) & 1u);
    return (ushort)(u >> 16);
}

// ---------------------------------------------------------------------------
// Kernel 1 [r26, scramble REVERTED — r11 measured +2.3 us from it]:
// packed-f16 pair sorting + wave-uniform scalarization. 54.7 us, VALU-bound.
// ---------------------------------------------------------------------------
__global__ __launch_bounds__(1024, 2) void k_inner(
    const float* __restrict__ M,      // 3 x 30
    const float* __restrict__ Ws_in,  // 181 x 3
    const float* __restrict__ Wd_in,  // 181 x 27
    const float* __restrict__ Wout,   // 181 x 190
    ushort* __restrict__ Abf,         // 192 x 192 bf16 out
    ushort* __restrict__ vec)         // PP x VLD (bf16)
{
    __shared__ float Gs[NPTS * 32];
    __shared__ float WsS[192 * 3];
    __shared__ float WdS[192 * 28];

    const int tid = threadIdx.x;

    {
        int gid = blockIdx.x * 1024 + tid;
        if (gid < 192 * 192) {
            int k = gid / 192, d = gid - k * 192;
            Abf[gid] = (k < KK && d < DEMB) ? f2bf(Wout[k * DEMB + d]) : (ushort)0;
        }
    }

    for (int i = tid; i < 192 * 3; i += 1024) WsS[i] = (i < KK * 3) ? Ws_in[i] : 0.f;
    for (int i = tid; i < 192 * 28; i += 1024) {
        int k = i / 28, m = i - k * 28;
        WdS[i] = (k < KK && m < 27) ? Wd_in[k * 27 + m] : 0.f;
    }
    for (int e = tid; e < NPTS * 32; e += 1024) {
        int a = e >> 5, b = e & 31;
        Gs[e] = (b < NPTS)
            ? (M[a] * M[b] + M[NPTS + a] * M[NPTS + b] + M[2 * NPTS + a] * M[2 * NPTS + b])
            : 0.f;
    }
    __syncthreads();

    const int wave = __builtin_amdgcn_readfirstlane(tid >> 6);  // wave-uniform
    const int lane = tid & 63;
    const int wid = blockIdx.x * 16 + wave;   // 0..8191, uniform
    const int chunk = wid % 3;
    const int pstream = wid / 3;              // 0..2730
    const int nstream = (chunk == 2) ? 2730 : 2731;
    const int k = chunk * 64 + lane;

    const float INF = __builtin_inff();
    const bool kvalid = (k < KK);
    const float w0 = WsS[k * 3 + 0];
    const float w1 = WsS[k * 3 + 1];
    const float w2 = WsS[k * 3 + 2];
    const float* wd = WdS + k * 28;

    const int NPAIR = PP / 2;   // 12180

    for (int t = pstream; t < NPAIR; t += nstream) {
        const int p0 = 2 * t;                 // uniform
        int i0 = p0 / 812;                    // 812 = 29*28  (scalar magic-div)
        int r  = p0 - i0 * 812;
        int i1 = r / 28;
        int i2 = r - i1 * 28;
        int c0 = i0;
        int c1 = i1 + (i1 >= c0 ? 1 : 0);
        int lo = min(c0, c1), hi = max(c0, c1);
        int c2a = i2;
        if (c2a >= lo) c2a++;
        if (c2a >= hi) c2a++;
        int c2b = i2 + 1;
        if (c2b >= lo) c2b++;
        if (c2b >= hi) c2b++;

        ushort* vrow0 = vec + (long)p0 * VLD;
        ushort* vrow1 = vrow0 + VLD;

        if (chunk == 0 && lane < 9) {
            int i = lane / 3, j = lane % 3;
            int cia = (i == 0) ? c0 : ((i == 1) ? c1 : c2a);
            int cja = (j == 0) ? c0 : ((j == 1) ? c1 : c2a);
            vrow0[lane] = f2bf(Gs[(cia << 5) + cja]);
            int cib = (i == 0) ? c0 : ((i == 1) ? c1 : c2b);
            int cjb = (j == 0) ? c0 : ((j == 1) ? c1 : c2b);
            vrow1[lane] = f2bf(Gs[(cib << 5) + cjb]);
        }

        const float* g0 = Gs + (c0 << 5);
        const float* g1 = Gs + (c1 << 5);
        const float* ga = Gs + (c2a << 5);
        const float* gb = Gs + (c2b << 5);
        const unsigned basem = (1u << c0) | (1u << c1);   // uniform
        const unsigned maska = basem | (1u << c2a);       // uniform
        const unsigned maskb = basem | (1u << c2b);       // uniform

        h2 s[30];
#pragma unroll
        for (int q = 0; q < 8; ++q) {
            float4 x0 = *(const float4*)&g0[q * 4];
            float4 x1 = *(const float4*)&g1[q * 4];
            float4 xa = *(const float4*)&ga[q * 4];
            float4 xb = *(const float4*)&gb[q * 4];
            int j0 = q * 4;
            if (j0 + 0 < NPTS) {
                float c = w0 * x0.x + w1 * x1.x;
                float va = w2 * xa.x + c;
                float vb = w2 * xb.x + c;
                va = ((maska >> (j0 + 0)) & 1u) ? INF : va;
                vb = ((maskb >> (j0 + 0)) & 1u) ? INF : vb;
                s[j0 + 0] = __builtin_amdgcn_cvt_pkrtz(va, vb);
            }
            if (j0 + 1 < NPTS) {
                float c = w0 * x0.y + w1 * x1.y;
                float va = w2 * xa.y + c;
                float vb = w2 * xb.y + c;
                va = ((maska >> (j0 + 1)) & 1u) ? INF : va;
                vb = ((maskb >> (j0 + 1)) & 1u) ? INF : vb;
                s[j0 + 1] = __builtin_amdgcn_cvt_pkrtz(va, vb);
            }
            if (j0 + 2 < NPTS) {
                float c = w0 * x0.z + w1 * x1.z;
                float va = w2 * xa.z + c;
                float vb = w2 * xb.z + c;
                va = ((maska >> (j0 + 2)) & 1u) ? INF : va;
                vb = ((maskb >> (j0 + 2)) & 1u) ? INF : vb;
                s[j0 + 2] = __builtin_amdgcn_cvt_pkrtz(va, vb);
            }
            if (j0 + 3 < NPTS) {
                float c = w0 * x0.w + w1 * x1.w;
                float va = w2 * xa.w + c;
                float vb = w2 * xb.w + c;
                va = ((maska >> (j0 + 3)) & 1u) ? INF : va;
                vb = ((maskb >> (j0 + 3)) & 1u) ? INF : vb;
                s[j0 + 3] = __builtin_amdgcn_cvt_pkrtz(va, vb);
            }
        }

        // Batcher odd-even mergesort, pruned, packed pairs
#pragma unroll
        for (int pw = 1; pw < 32; pw <<= 1) {
#pragma unroll
            for (int kk = pw; kk >= 1; kk >>= 1) {
#pragma unroll
                for (int j = kk % pw; j + kk < 32; j += 2 * kk) {
#pragma unroll
                    for (int i = 0; i < kk; ++i) {
                        int a = i + j, b = i + j + kk;
                        if (a / (pw * 2) == b / (pw * 2) && b < 30
                            && !(pw == 16 && a == 27)) {
                            h2 x = s[a], y = s[b];
                            s[a] = __builtin_elementwise_min(x, y);
                            s[b] = __builtin_elementwise_max(x, y);
                        }
                    }
                }
            }
        }

        if (kvalid) {
            float emb0 = 0.f, emb1 = 0.f;
#pragma unroll
            for (int j = 0; j < 24; j += 4) {
                float4 w4 = *(const float4*)&wd[j];
                emb0 += w4.x * (float)s[j + 0].x + w4.y * (float)s[j + 1].x
                      + w4.z * (float)s[j + 2].x + w4.w * (float)s[j + 3].x;
                emb1 += w4.x * (float)s[j + 0].y + w4.y * (float)s[j + 1].y
                      + w4.z * (float)s[j + 2].y + w4.w * (float)s[j + 3].y;
            }
            {
                float4 w4 = *(const float4*)&wd[24];
                emb0 += w4.x * (float)s[24].x + w4.y * (float)s[25].x
                      + w4.z * (float)s[26].x;
                emb1 += w4.x * (float)s[24].y + w4.y * (float)s[25].y
                      + w4.z * (float)s[26].y;
            }
            vrow0[9 + k] = f2bf(emb0);
            vrow1[9 + k] = f2bf(emb1);
        } else if (k < 183) {
            vrow0[9 + k] = 0;
            vrow1[9 + k] = 0;
        }
    }
}

// ---------------------------------------------------------------------------
// Kernel 2 [r27+SNPS, + out-zeroing for k_hist quarter atomics]:
// grid 1536, direct 16B loads, swapped MFMA operands -> packed 8B stores.
// ---------------------------------------------------------------------------
__global__ __launch_bounds__(256) void k_gemm(
    const ushort* __restrict__ vecB,  // PP x 192 bf16
    const ushort* __restrict__ Abf,   // 192 x 192 bf16
    ushort* __restrict__ sm2TP,       // 181 x SNPS u16 encoded keys
    float* __restrict__ out)          // 181 (zeroed here; hist accumulates)
{
    const int tid  = threadIdx.x;
    const int bid  = blockIdx.x;
    const int tile = bid >> 2;        // p-tile (64 p's)
    const int qtr  = bid & 3;         // kt quarter: 3 kt each
    const int wave = tid >> 6;
    const int lane = tid & 63;
    const int n = lane & 15;
    const int quad = lane >> 4;

    if (bid == 0 && tid < KK) out[tid] = 0.f;

    const int prow = tile * 64 + wave * 16 + n;
    bf16x8 afrag[6];
    {
        const ushort* row = vecB + (size_t)prow * VLD;
#pragma unroll
        for (int kc = 0; kc < 6; ++kc)
            afrag[kc] = *(const bf16x8*)&row[kc * 32 + quad * 8];
    }

    const int pb = tile * 64 + wave * 16 + quad * 4;  // lane's 4 consecutive p

#pragma unroll
    for (int i = 0; i < 3; ++i) {
        const int kt = qtr * 3 + i;
        const int kg = kt * 16 + n;
        f32x4 acc = {0.f, 0.f, 0.f, 0.f};
        const ushort* arow = Abf + kg * 192;
#pragma unroll
        for (int kc = 0; kc < 6; ++kc) {
            bf16x8 bfrag = *(const bf16x8*)&arow[kc * 32 + quad * 8];
            acc = __builtin_amdgcn_mfma_f32_16x16x32_bf16(afrag[kc], bfrag, acc, 0, 0, 0);
        }
        if (kg < KK) {
            u16x4 st;
#pragma unroll
            for (int r = 0; r < 4; ++r) {
                int p = pb + r;
                unsigned e;
                if (p < PP) {
                    unsigned u = __float_as_uint(acc[r]);
                    u = (u & 0x80000000u) ? ~u : (u | 0x80000000u);
                    e = (u + 0x8000u) >> 16;     // RTN 16-bit monotone key
                } else {
                    e = 0xFFFFu;                 // pad sorts strictly last
                }
                st[r] = (ushort)e;
            }
            *(u16x4*)&sm2TP[(size_t)kg * SNPS + pb] = st;  // 8B aligned
        }
    }
}

// ---------------------------------------------------------------------------
// Kernel 3 (r33): QUARTER-SPLIT rank-scatter. r32's single-sweep reverted
// (returning count-atomics doubled LDS-pipe cost: H 25 -> 50). Instead fix
// the SHAPE: r29 ran 181 blocks @ 112KB = 1 block/CU, 75 CUs idle, per-block
// LDS pipeline on all 24576 keys. Now: block (k, q) handles key-space
// quarter [q<<14, (q+1)<<14): hist 16384 bins u16-packed = 32KB + sv 48KB
// = exactly 80KB -> 2 blocks/CU (full 160KB pool); scan scratch lives inside
// sv (consumed before sv is written). Grid 724; per-CU LDS work ~0.7x r29,
// scan cost /3. Two-sweep ranking (count fire-and-forget, rank returning).
// Dot: this quarter's elements are globally ranked [below_tot, below_tot+tot)
// -> contiguous wrow segment vs sv[0..tot); cap at PP drops pads. atomicAdd
// partials into out[k] (zeroed in k_gemm). __launch_bounds__(1024,8) caps
// VGPR at 64 for 2-block residency; live regs ~45 (kv 12 + w 8 + temps).
// ---------------------------------------------------------------------------
__global__ __launch_bounds__(1024, 8) void k_hist(
    const ushort* __restrict__ sm2TP,    // 181 x SNPS u16 keys (padded)
    const float* __restrict__ WdOut,     // 181 x PP
    float* __restrict__ out)             // 181 (accumulated)
{
    __shared__ unsigned hist[8192];      // 32 KiB: 16384 bins u16-packed
    __shared__ ushort sv[SNP];           // 48 KiB local-rank value bits
    unsigned* scr = (unsigned*)sv;       // 16-word wave scratch inside sv

    const int tid  = threadIdx.x;
    const int wave = tid >> 6;
    const int lane = tid & 63;
    const int k = blockIdx.x >> 2;
    const int q = blockIdx.x & 3;
    const unsigned qbase = (unsigned)q << 14;

    const ushort* rowU = sm2TP + (size_t)k * SNPS;
    const float* wrow  = WdOut + (size_t)k * PP;

    for (int i = tid; i < 2048; i += 1024)
        ((u32x4*)hist)[i] = (u32x4){0u, 0u, 0u, 0u};
    __syncthreads();

    // load keys -> regs; count this quarter (fire-and-forget) + below-count
    u16x4 kv[6];
    unsigned below = 0;
#pragma unroll
    for (int j = 0; j < 6; ++j) {
        kv[j] = *(const u16x4*)&rowU[tid * 4 + j * 4096];
#pragma unroll
        for (int e = 0; e < 4; ++e) {
            unsigned u = kv[j][e];
            unsigned rel = u - qbase;
            if (rel < 16384u) {
                unsigned wd = rel >> 1;
                atomicAdd(&hist[((wd & 7u) << 10) + (wd >> 3)],
                          1u << ((rel & 1u) << 4));
            } else {
                below += (u < qbase) ? 1u : 0u;
            }
        }
    }
#pragma unroll
    for (int off = 32; off > 0; off >>= 1)
        below += (unsigned)__shfl_down((int)below, off, 64);
    if (lane == 0) scr[wave] = below;
    __syncthreads();                      // hist + scr complete
    unsigned below_tot = 0;
#pragma unroll
    for (int ww = 0; ww < 16; ++ww) below_tot += scr[ww];
    __syncthreads();                      // scr reads done before reuse

    // CDF scan: thread owns transposed words (i<<10)+tid = bins [16t,16t+16)
    unsigned w[8];
    unsigned tsum = 0;
#pragma unroll
    for (int i = 0; i < 8; ++i) {
        w[i] = hist[(i << 10) + tid];
        tsum += (w[i] & 0xFFFFu) + (w[i] >> 16);
    }
    unsigned inc = tsum;
#pragma unroll
    for (int off = 1; off < 64; off <<= 1) {
        unsigned o = (unsigned)__shfl_up((int)inc, off, 64);
        if (lane >= off) inc += o;
    }
    if (lane == 63) scr[wave] = inc;
    __syncthreads();
    unsigned wbase = 0, tot = 0;
#pragma unroll
    for (int ww = 0; ww < 16; ++ww) {
        unsigned t = scr[ww];
        tot += t;
        wbase += (ww < wave) ? t : 0u;
    }
    __syncthreads();                      // scr consumed; sv now writable

    unsigned running = wbase + (inc - tsum);   // LOCAL 0-based quarter rank
#pragma unroll
    for (int i = 0; i < 8; ++i) {
        unsigned lob = running;
        running += (w[i] & 0xFFFFu);
        unsigned hib = running;
        running += (w[i] >> 16);
        hist[(i << 10) + tid] = lob | (hib << 16);
    }
    __syncthreads();

    // rank sweep (returning atomics) + scatter value bits into sv
#pragma unroll
    for (int j = 0; j < 6; ++j) {
#pragma unroll
        for (int e = 0; e < 4; ++e) {
            unsigned u = kv[j][e];
            unsigned rel = u - qbase;
            if (rel < 16384u) {
                unsigned wd = rel >> 1;
                unsigned sh = (rel & 1u) << 4;
                unsigned old = atomicAdd(&hist[((wd & 7u) << 10) + (wd >> 3)],
                                         1u << sh);
                unsigned r = (old >> sh) & 0xFFFFu;
                unsigned raw16 = (u & 0x8000u) ? (u & 0x7FFFu)
                                               : ((~u) & 0xFFFFu);
                sv[r] = (ushort)raw16;
            }
        }
    }
    __syncthreads();

    // dot over this quarter's contiguous global-rank segment; cap drops pads
    float acc = 0.f;
    int cap = min((int)tot, PP - (int)below_tot);
    for (int i = tid; i < cap; i += 1024)
        acc += wrow[below_tot + i] * __uint_as_float((unsigned)sv[i] << 16);

#pragma unroll
    for (int off = 32; off > 0; off >>= 1)
        acc += __shfl_down(acc, off, 64);
    __syncthreads();                      // sv reads done before scr reuse
    if (lane == 0) ((float*)scr)[wave] = acc;
    __syncthreads();
    if (tid == 0) {
        float t = 0.f;
#pragma unroll
        for (int ww = 0; ww < 16; ++ww) t += ((float*)scr)[ww];
        atomicAdd(&out[k], t);
    }
}

// ---------------------------------------------------------------------------
extern "C" void kernel_launch(void* const* d_in, const int* in_sizes, int n_in,
                              void* d_out, int out_size, void* d_ws, size_t ws_size,
                              hipStream_t stream) {
    const float* M      = (const float*)d_in[0];
    const float* Ws_in  = (const float*)d_in[1];
    const float* Wd_in  = (const float*)d_in[2];
    const float* Ws_out = (const float*)d_in[3];
    const float* Wd_out = (const float*)d_in[4];
    float* out = (float*)d_out;

    // workspace layout (~18.4 MB):
    // [0, 9.36 MB):        vecB (PP x 192 bf16)
    // [9.36, +74KB):       Abf (192 x 192 bf16)
    // [9.43, +8.91 MB):    sm2TP (181 x SNPS u16 keys)
    char* ws = (char*)d_ws;
    ushort* vecB  = (ushort*)ws;
    ushort* Abf   = (ushort*)(ws + (size_t)PP * VLD * 2);
    ushort* sm2TP = (ushort*)(ws + (size_t)PP * VLD * 2 + (size_t)192 * 192 * 2);

    k_inner<<<512, 1024, 0, stream>>>(M, Ws_in, Wd_in, Ws_out, Abf, vecB);

    k_gemm<<<(SNP / 64) * 4, 256, 0, stream>>>(vecB, Abf, sm2TP, out);

    k_hist<<<KK * 4, 1024, 0, stream>>>(sm2TP, Wd_out, out);
}

// Round 14
// 160.286 us; speedup vs baseline: 1.4286x; 1.4286x over previous
//
#include <hip/hip_runtime.h>
#include <hip/hip_bf16.h>

#define DIMK 3
#define NPTS 30
#define KK   181
#define PP   24360
#define DEMB 190
#define VLD  192   // padded vec row stride (bf16 elements)
#define SNP  24576 // logical sort-row length (16*1536)
#define SNPS 24608 // padded sm2TP row stride (+64B, breaks pow2 aliasing)

typedef __attribute__((ext_vector_type(8))) short bf16x8;
typedef __attribute__((ext_vector_type(4))) float f32x4;
typedef __attribute__((ext_vector_type(2))) __fp16 h2;
typedef __attribute__((ext_vector_type(4))) ushort u16x4;
typedef __attribute__((ext_vector_type(4))) unsigned u32x4;

__device__ __forceinline__ ushort f2bf(float f) {
    unsigned u = __float_as_uint(f);
    u += 0x7FFFu + ((u >> 16) & 1u);
    return (ushort)(u >> 16);
}

// ---------------------------------------------------------------------------
// Kernel 1 [r26 — best measured: 54.7 us, VALU-bound 73%, VGPR 44]:
// packed-f16 pair sorting + wave-uniform scalarization.
// REJECTED variants (measured): stream scramble (+2.3 us, r11), half-grid
// split (+6 us overhead, r9).
// ---------------------------------------------------------------------------
__global__ __launch_bounds__(1024, 2) void k_inner(
    const float* __restrict__ M,      // 3 x 30
    const float* __restrict__ Ws_in,  // 181 x 3
    const float* __restrict__ Wd_in,  // 181 x 27
    const float* __restrict__ Wout,   // 181 x 190
    ushort* __restrict__ Abf,         // 192 x 192 bf16 out
    ushort* __restrict__ vec)         // PP x VLD (bf16)
{
    __shared__ float Gs[NPTS * 32];
    __shared__ float WsS[192 * 3];
    __shared__ float WdS[192 * 28];

    const int tid = threadIdx.x;

    {
        int gid = blockIdx.x * 1024 + tid;
        if (gid < 192 * 192) {
            int k = gid / 192, d = gid - k * 192;
            Abf[gid] = (k < KK && d < DEMB) ? f2bf(Wout[k * DEMB + d]) : (ushort)0;
        }
    }

    for (int i = tid; i < 192 * 3; i += 1024) WsS[i] = (i < KK * 3) ? Ws_in[i] : 0.f;
    for (int i = tid; i < 192 * 28; i += 1024) {
        int k = i / 28, m = i - k * 28;
        WdS[i] = (k < KK && m < 27) ? Wd_in[k * 27 + m] : 0.f;
    }
    for (int e = tid; e < NPTS * 32; e += 1024) {
        int a = e >> 5, b = e & 31;
        Gs[e] = (b < NPTS)
            ? (M[a] * M[b] + M[NPTS + a] * M[NPTS + b] + M[2 * NPTS + a] * M[2 * NPTS + b])
            : 0.f;
    }
    __syncthreads();

    const int wave = __builtin_amdgcn_readfirstlane(tid >> 6);  // wave-uniform
    const int lane = tid & 63;
    const int wid = blockIdx.x * 16 + wave;   // 0..8191, uniform
    const int chunk = wid % 3;
    const int pstream = wid / 3;              // 0..2730
    const int nstream = (chunk == 2) ? 2730 : 2731;
    const int k = chunk * 64 + lane;

    const float INF = __builtin_inff();
    const bool kvalid = (k < KK);
    const float w0 = WsS[k * 3 + 0];
    const float w1 = WsS[k * 3 + 1];
    const float w2 = WsS[k * 3 + 2];
    const float* wd = WdS + k * 28;

    const int NPAIR = PP / 2;   // 12180

    for (int t = pstream; t < NPAIR; t += nstream) {
        const int p0 = 2 * t;                 // uniform
        int i0 = p0 / 812;                    // 812 = 29*28  (scalar magic-div)
        int r  = p0 - i0 * 812;
        int i1 = r / 28;
        int i2 = r - i1 * 28;
        int c0 = i0;
        int c1 = i1 + (i1 >= c0 ? 1 : 0);
        int lo = min(c0, c1), hi = max(c0, c1);
        int c2a = i2;
        if (c2a >= lo) c2a++;
        if (c2a >= hi) c2a++;
        int c2b = i2 + 1;
        if (c2b >= lo) c2b++;
        if (c2b >= hi) c2b++;

        ushort* vrow0 = vec + (long)p0 * VLD;
        ushort* vrow1 = vrow0 + VLD;

        if (chunk == 0 && lane < 9) {
            int i = lane / 3, j = lane % 3;
            int cia = (i == 0) ? c0 : ((i == 1) ? c1 : c2a);
            int cja = (j == 0) ? c0 : ((j == 1) ? c1 : c2a);
            vrow0[lane] = f2bf(Gs[(cia << 5) + cja]);
            int cib = (i == 0) ? c0 : ((i == 1) ? c1 : c2b);
            int cjb = (j == 0) ? c0 : ((j == 1) ? c1 : c2b);
            vrow1[lane] = f2bf(Gs[(cib << 5) + cjb]);
        }

        const float* g0 = Gs + (c0 << 5);
        const float* g1 = Gs + (c1 << 5);
        const float* ga = Gs + (c2a << 5);
        const float* gb = Gs + (c2b << 5);
        const unsigned basem = (1u << c0) | (1u << c1);   // uniform
        const unsigned maska = basem | (1u << c2a);       // uniform
        const unsigned maskb = basem | (1u << c2b);       // uniform

        h2 s[30];
#pragma unroll
        for (int q = 0; q < 8; ++q) {
            float4 x0 = *(const float4*)&g0[q * 4];
            float4 x1 = *(const float4*)&g1[q * 4];
            float4 xa = *(const float4*)&ga[q * 4];
            float4 xb = *(const float4*)&gb[q * 4];
            int j0 = q * 4;
            if (j0 + 0 < NPTS) {
                float c = w0 * x0.x + w1 * x1.x;
                float va = w2 * xa.x + c;
                float vb = w2 * xb.x + c;
                va = ((maska >> (j0 + 0)) & 1u) ? INF : va;
                vb = ((maskb >> (j0 + 0)) & 1u) ? INF : vb;
                s[j0 + 0] = __builtin_amdgcn_cvt_pkrtz(va, vb);
            }
            if (j0 + 1 < NPTS) {
                float c = w0 * x0.y + w1 * x1.y;
                float va = w2 * xa.y + c;
                float vb = w2 * xb.y + c;
                va = ((maska >> (j0 + 1)) & 1u) ? INF : va;
                vb = ((maskb >> (j0 + 1)) & 1u) ? INF : vb;
                s[j0 + 1] = __builtin_amdgcn_cvt_pkrtz(va, vb);
            }
            if (j0 + 2 < NPTS) {
                float c = w0 * x0.z + w1 * x1.z;
                float va = w2 * xa.z + c;
                float vb = w2 * xb.z + c;
                va = ((maska >> (j0 + 2)) & 1u) ? INF : va;
                vb = ((maskb >> (j0 + 2)) & 1u) ? INF : vb;
                s[j0 + 2] = __builtin_amdgcn_cvt_pkrtz(va, vb);
            }
            if (j0 + 3 < NPTS) {
                float c = w0 * x0.w + w1 * x1.w;
                float va = w2 * xa.w + c;
                float vb = w2 * xb.w + c;
                va = ((maska >> (j0 + 3)) & 1u) ? INF : va;
                vb = ((maskb >> (j0 + 3)) & 1u) ? INF : vb;
                s[j0 + 3] = __builtin_amdgcn_cvt_pkrtz(va, vb);
            }
        }

        // Batcher odd-even mergesort, pruned, packed pairs
#pragma unroll
        for (int pw = 1; pw < 32; pw <<= 1) {
#pragma unroll
            for (int kk = pw; kk >= 1; kk >>= 1) {
#pragma unroll
                for (int j = kk % pw; j + kk < 32; j += 2 * kk) {
#pragma unroll
                    for (int i = 0; i < kk; ++i) {
                        int a = i + j, b = i + j + kk;
                        if (a / (pw * 2) == b / (pw * 2) && b < 30
                            && !(pw == 16 && a == 27)) {
                            h2 x = s[a], y = s[b];
                            s[a] = __builtin_elementwise_min(x, y);
                            s[b] = __builtin_elementwise_max(x, y);
                        }
                    }
                }
            }
        }

        if (kvalid) {
            float emb0 = 0.f, emb1 = 0.f;
#pragma unroll
            for (int j = 0; j < 24; j += 4) {
                float4 w4 = *(const float4*)&wd[j];
                emb0 += w4.x * (float)s[j + 0].x + w4.y * (float)s[j + 1].x
                      + w4.z * (float)s[j + 2].x + w4.w * (float)s[j + 3].x;
                emb1 += w4.x * (float)s[j + 0].y + w4.y * (float)s[j + 1].y
                      + w4.z * (float)s[j + 2].y + w4.w * (float)s[j + 3].y;
            }
            {
                float4 w4 = *(const float4*)&wd[24];
                emb0 += w4.x * (float)s[24].x + w4.y * (float)s[25].x
                      + w4.z * (float)s[26].x;
                emb1 += w4.x * (float)s[24].y + w4.y * (float)s[25].y
                      + w4.z * (float)s[26].y;
            }
            vrow0[9 + k] = f2bf(emb0);
            vrow1[9 + k] = f2bf(emb1);
        } else if (k < 183) {
            vrow0[9 + k] = 0;
            vrow1[9 + k] = 0;
        }
    }
}

// ---------------------------------------------------------------------------
// Kernel 2 [r27+SNPS — part of the 160.4 us best]: grid 1536 (p-tile x
// kt-quarter, 256 thr, 24 waves/CU), direct 16B loads (no LDS staging; zero
// inter-wave reuse), swapped MFMA operands -> packed 8B coalesced key stores.
// REJECTED (measured): merged grid-384 (occupancy loss, r5/r6 era).
// ---------------------------------------------------------------------------
__global__ __launch_bounds__(256) void k_gemm(
    const ushort* __restrict__ vecB,  // PP x 192 bf16
    const ushort* __restrict__ Abf,   // 192 x 192 bf16
    ushort* __restrict__ sm2TP)       // 181 x SNPS u16 encoded keys
{
    const int tid  = threadIdx.x;
    const int bid  = blockIdx.x;
    const int tile = bid >> 2;        // p-tile (64 p's)
    const int qtr  = bid & 3;         // kt quarter: 3 kt each
    const int wave = tid >> 6;
    const int lane = tid & 63;
    const int n = lane & 15;
    const int quad = lane >> 4;

    const int prow = tile * 64 + wave * 16 + n;
    bf16x8 afrag[6];
    {
        const ushort* row = vecB + (size_t)prow * VLD;
#pragma unroll
        for (int kc = 0; kc < 6; ++kc)
            afrag[kc] = *(const bf16x8*)&row[kc * 32 + quad * 8];
    }

    const int pb = tile * 64 + wave * 16 + quad * 4;  // lane's 4 consecutive p

#pragma unroll
    for (int i = 0; i < 3; ++i) {
        const int kt = qtr * 3 + i;
        const int kg = kt * 16 + n;
        f32x4 acc = {0.f, 0.f, 0.f, 0.f};
        const ushort* arow = Abf + kg * 192;
#pragma unroll
        for (int kc = 0; kc < 6; ++kc) {
            bf16x8 bfrag = *(const bf16x8*)&arow[kc * 32 + quad * 8];
            acc = __builtin_amdgcn_mfma_f32_16x16x32_bf16(afrag[kc], bfrag, acc, 0, 0, 0);
        }
        if (kg < KK) {
            u16x4 st;
#pragma unroll
            for (int r = 0; r < 4; ++r) {
                int p = pb + r;
                unsigned e;
                if (p < PP) {
                    unsigned u = __float_as_uint(acc[r]);
                    u = (u & 0x80000000u) ? ~u : (u | 0x80000000u);
                    e = (u + 0x8000u) >> 16;     // RTN 16-bit monotone key
                } else {
                    e = 0xFFFFu;                 // pad sorts strictly last
                }
                st[r] = (ushort)e;
            }
            *(u16x4*)&sm2TP[(size_t)kg * SNPS + pb] = st;  // 8B aligned
        }
    }
}

// ---------------------------------------------------------------------------
// Kernel 3 [r29 — part of the 160.4 us best]: rank-scatter, two-sweep,
// (1024,1) so the allocator is unconstrained (~a few dozen VGPR live, no
// spill). One block per k; two 32768-bin key-space passes over a u16-packed
// hist (64KB) + sv[SNP] (48KB) = 112.5KB -> 1 block/CU.
// REJECTED (measured): single returning-atomic sweep (r32: LDS-pipe 2x,
// H 25->50); quarter-split @(1024,8) (r33: VGPR 32, 170MB spill, 92 us);
// wrow register prefetch (r31: tipped allocator into 64-pin spill).
// ---------------------------------------------------------------------------
__global__ __launch_bounds__(1024, 1) void k_hist(
    const ushort* __restrict__ sm2TP,    // 181 x SNPS u16 keys (padded)
    const float* __restrict__ WdOut,     // 181 x PP
    float* __restrict__ out)             // 181
{
    __shared__ unsigned hist[16384];     // 64 KiB (u16-packed, 32768 bins/pass)
    __shared__ ushort sv[SNP];           // 48 KiB rank-indexed value bits
    __shared__ unsigned wred[16];
    __shared__ float fred[16];

    const int tid  = threadIdx.x;
    const int wave = tid >> 6;
    const int lane = tid & 63;
    const int k    = blockIdx.x;

    const ushort* rowU = sm2TP + (size_t)k * SNPS;
    const float* wrow  = WdOut + (size_t)k * PP;

    // keys -> registers, coalesced 8B loads
    u16x4 kv[6];
#pragma unroll
    for (int j = 0; j < 6; ++j)
        kv[j] = *(const u16x4*)&rowU[tid * 4 + j * 4096];

    unsigned below = 0;
    for (int p2 = 0; p2 < 2; ++p2) {
        const unsigned kbase = (unsigned)p2 << 15;

        for (int i = tid; i < 4096; i += 1024)
            ((u32x4*)hist)[i] = (u32x4){0u, 0u, 0u, 0u};
        __syncthreads();

        // count (fire-and-forget atomics)
#pragma unroll
        for (int j = 0; j < 6; ++j) {
#pragma unroll
            for (int e = 0; e < 4; ++e) {
                unsigned u = kv[j][e];
                unsigned rel = u - kbase;
                if (rel < 32768u) {
                    unsigned wd = rel >> 1;
                    atomicAdd(&hist[((wd & 15u) << 10) + (wd >> 4)],
                              1u << ((rel & 1u) << 4));
                }
            }
        }
        __syncthreads();

        // CDF scan: thread owns transposed words (i<<10)+tid
        unsigned w[16];
        unsigned tsum = 0;
#pragma unroll
        for (int i = 0; i < 16; ++i) {
            w[i] = hist[(i << 10) + tid];
            tsum += (w[i] & 0xFFFFu) + (w[i] >> 16);
        }
        unsigned inc = tsum;
#pragma unroll
        for (int off = 1; off < 64; off <<= 1) {
            unsigned o = (unsigned)__shfl_up((int)inc, off, 64);
            if (lane >= off) inc += o;
        }
        if (lane == 63) wred[wave] = inc;
        __syncthreads();
        unsigned wbase = 0, tot = 0;
#pragma unroll
        for (int ww = 0; ww < 16; ++ww) {
            unsigned t = wred[ww];
            tot += t;
            wbase += (ww < wave) ? t : 0u;
        }

        unsigned running = below + wbase + (inc - tsum);
#pragma unroll
        for (int i = 0; i < 16; ++i) {
            unsigned lob = running;
            running += (w[i] & 0xFFFFu);
            unsigned hib = running;
            running += (w[i] >> 16);
            hist[(i << 10) + tid] = lob | (hib << 16);   // own words only
        }
        __syncthreads();

        // per-element rank (returning atomics) + scatter value bits
#pragma unroll
        for (int j = 0; j < 6; ++j) {
#pragma unroll
            for (int e = 0; e < 4; ++e) {
                unsigned u = kv[j][e];
                unsigned rel = u - kbase;
                if (rel < 32768u) {
                    unsigned wd = rel >> 1;
                    unsigned sh = (rel & 1u) << 4;
                    unsigned old = atomicAdd(&hist[((wd & 15u) << 10) + (wd >> 4)],
                                             1u << sh);
                    unsigned r = (old >> sh) & 0xFFFFu;
                    unsigned raw16 = (u & 0x8000u) ? (u & 0x7FFFu)
                                                   : ((~u) & 0xFFFFu);
                    sv[r] = (ushort)raw16;
                }
            }
        }
        below += tot;
        __syncthreads();
    }

    // coalesced fused dot (wrow from HBM, sv from LDS)
    float acc = 0.f;
#pragma unroll
    for (int j = 0; j < 6; ++j) {
        int i4 = tid * 4 + j * 4096;
        if (i4 < PP) {   // PP % 4 == 0: whole-vector cut, no partials
            u16x4 s4 = *(const u16x4*)&sv[i4];
            float4 w4 = *(const float4*)&wrow[i4];
            acc += w4.x * __uint_as_float((unsigned)s4[0] << 16)
                 + w4.y * __uint_as_float((unsigned)s4[1] << 16)
                 + w4.z * __uint_as_float((unsigned)s4[2] << 16)
                 + w4.w * __uint_as_float((unsigned)s4[3] << 16);
        }
    }

#pragma unroll
    for (int off = 32; off > 0; off >>= 1)
        acc += __shfl_down(acc, off, 64);
    if (lane == 0) fred[wave] = acc;
    __syncthreads();
    if (tid == 0) {
        float t = 0.f;
#pragma unroll
        for (int ww = 0; ww < 16; ++ww) t += fred[ww];
        out[k] = t;
    }
}

// ---------------------------------------------------------------------------
extern "C" void kernel_launch(void* const* d_in, const int* in_sizes, int n_in,
                              void* d_out, int out_size, void* d_ws, size_t ws_size,
                              hipStream_t stream) {
    const float* M      = (const float*)d_in[0];
    const float* Ws_in  = (const float*)d_in[1];
    const float* Wd_in  = (const float*)d_in[2];
    const float* Ws_out = (const float*)d_in[3];
    const float* Wd_out = (const float*)d_in[4];
    float* out = (float*)d_out;

    // workspace layout (~18.4 MB):
    // [0, 9.36 MB):        vecB (PP x 192 bf16)
    // [9.36, +74KB):       Abf (192 x 192 bf16)
    // [9.43, +8.91 MB):    sm2TP (181 x SNPS u16 keys)
    char* ws = (char*)d_ws;
    ushort* vecB  = (ushort*)ws;
    ushort* Abf   = (ushort*)(ws + (size_t)PP * VLD * 2);
    ushort* sm2TP = (ushort*)(ws + (size_t)PP * VLD * 2 + (size_t)192 * 192 * 2);

    k_inner<<<512, 1024, 0, stream>>>(M, Ws_in, Wd_in, Ws_out, Abf, vecB);

    k_gemm<<<(SNP / 64) * 4, 256, 0, stream>>>(vecB, Abf, sm2TP);

    k_hist<<<KK, 1024, 0, stream>>>(sm2TP, Wd_out, out);
}